// Round 2
// baseline (247.200 us; speedup 1.0000x reference)
//
#include <hip/hip_runtime.h>

__device__ __forceinline__ float fexp2(float x) { return __builtin_amdgcn_exp2f(x); }
__device__ __forceinline__ float flog2(float x) { return __builtin_amdgcn_logf(x); }

__device__ __forceinline__ float s2lin(float c) {
    float p = fexp2(flog2((c + 0.055f) * (1.0f / 1.055f)) * 2.4f);
    return c > 0.04045f ? p : c * (1.0f / 12.92f);
}

__device__ __forceinline__ float labf(float t) {
    float p = fexp2(flog2(t) * (1.0f / 3.0f));
    return t > 0.008856f ? p : 7.787f * t + (16.0f / 116.0f);
}

__device__ __forceinline__ void px(float r, float g, float b,
                                   float& L, float& a01, float& b01) {
    float lr = s2lin(r), lg = s2lin(g), lb = s2lin(b);
    // RGB2XYZ rows pre-divided by D65 white (0.95047, 1.0, 1.08883)
    float X = 0.43395300f * lr + 0.37621900f * lg + 0.18982460f * lb;
    float Y = 0.21267100f * lr + 0.71516000f * lg + 0.07216900f * lb;
    float Z = 0.01775660f * lr + 0.10946970f * lg + 0.87270740f * lb;
    float fx = labf(X), fy = labf(Y), fz = labf(Z);
    L   = 116.0f * fy - 16.0f;                              // L in [0,100]
    a01 = (500.0f * (fx - fy) + 128.0f) * (1.0f / 255.0f);
    b01 = (200.0f * (fy - fz) + 128.0f) * (1.0f / 255.0f);
}

// Process 4 consecutive pixels held in 3 float4 registers, in place.
// Lab layout after this: A = {L0,a0,b0,L1}, B = {a1,b1,L2,a2}, C = {b2,L3,a3,b3}
// -> L slots are A.x, A.w, B.z, C.y (rescaled later).
__device__ __forceinline__ void chunk4(float4& A, float4& B, float4& C,
                                       float& m1, float& m2) {
    float L, a, b;
    px(A.x, A.y, A.z, L, a, b); m1 = fminf(m1, L); m2 = fminf(m2, 100.0f - L);
    A.x = L; A.y = a; A.z = b;
    px(A.w, B.x, B.y, L, a, b); m1 = fminf(m1, L); m2 = fminf(m2, 100.0f - L);
    A.w = L; B.x = a; B.y = b;
    px(B.z, B.w, C.x, L, a, b); m1 = fminf(m1, L); m2 = fminf(m2, 100.0f - L);
    B.z = L; B.w = a; C.x = b;
    px(C.y, C.z, C.w, L, a, b); m1 = fminf(m1, L); m2 = fminf(m2, 100.0f - L);
    C.y = L; C.z = a; C.w = b;
}

// One block per image (16384 px), 1024 threads x 16 px.
// All 12 float4 loads issued up front (12 VMEM in flight per wave), Lab computed
// in place in registers at full f32 precision, block min-reduce, rescale L slots,
// 12 float4 stores. Single launch, no workspace.
__global__ __launch_bounds__(1024, 8) void k_fused(const float* __restrict__ x,
                                                   float* __restrict__ out) {
    const int img = blockIdx.x, t = threadIdx.x;
    const size_t base4 = (size_t)img * 12288;          // float4s per image
    const float4* __restrict__ in4 = (const float4*)x + base4;
    float4* __restrict__ o4 = (float4*)out + base4;

    // thread t, chunk c covers pixels 4*(t + 1024*c) .. +3  => float4s c*3072 + 3t + j
    float4 f[12];
#pragma unroll
    for (int c = 0; c < 4; ++c)
#pragma unroll
        for (int j = 0; j < 3; ++j)
            f[c * 3 + j] = in4[c * 3072 + 3 * t + j];

    float m1 = 3.4e38f, m2 = 3.4e38f;                  // min(L), min(100-L)
#pragma unroll
    for (int c = 0; c < 4; ++c)
        chunk4(f[c * 3], f[c * 3 + 1], f[c * 3 + 2], m1, m2);

    // wave reduce (64 lanes), then block reduce via tiny LDS
#pragma unroll
    for (int m = 32; m; m >>= 1) {
        m1 = fminf(m1, __shfl_xor(m1, m, 64));
        m2 = fminf(m2, __shfl_xor(m2, m, 64));
    }
    __shared__ float sm[32];                           // 16 waves x {minL, min(100-L)}
    if ((t & 63) == 0) { sm[(t >> 6) * 2] = m1; sm[(t >> 6) * 2 + 1] = m2; }
    __syncthreads();
    float Lmin = 3.4e38f, M2 = 3.4e38f;
#pragma unroll
    for (int i = 0; i < 16; ++i) {                     // broadcast reads, conflict-free
        Lmin = fminf(Lmin, sm[2 * i]);
        M2   = fminf(M2,   sm[2 * i + 1]);
    }
    const float s = 1.0f / ((100.0f - M2) - Lmin);

#pragma unroll
    for (int c = 0; c < 4; ++c) {                      // rescale the 4 L slots per chunk
        f[c * 3].x     = (f[c * 3].x     - Lmin) * s;
        f[c * 3].w     = (f[c * 3].w     - Lmin) * s;
        f[c * 3 + 1].z = (f[c * 3 + 1].z - Lmin) * s;
        f[c * 3 + 2].y = (f[c * 3 + 2].y - Lmin) * s;
    }

#pragma unroll
    for (int c = 0; c < 4; ++c)
#pragma unroll
        for (int j = 0; j < 3; ++j)
            o4[c * 3072 + 3 * t + j] = f[c * 3 + j];
}

extern "C" void kernel_launch(void* const* d_in, const int* in_sizes, int n_in,
                              void* d_out, int out_size, void* d_ws, size_t ws_size,
                              hipStream_t stream) {
    (void)in_sizes; (void)n_in; (void)out_size; (void)d_ws; (void)ws_size;
    const float* x = (const float*)d_in[0];
    float* out = (float*)d_out;
    k_fused<<<512, 1024, 0, stream>>>(x, out);
}

// Round 3
// 195.751 us; speedup vs baseline: 1.2628x; 1.2628x over previous
//
#include <hip/hip_runtime.h>

__device__ __forceinline__ float fexp2(float x) { return __builtin_amdgcn_exp2f(x); }
__device__ __forceinline__ float flog2(float x) { return __builtin_amdgcn_logf(x); }

__device__ __forceinline__ float s2lin(float c) {
    float p = fexp2(flog2((c + 0.055f) * (1.0f / 1.055f)) * 2.4f);
    return c > 0.04045f ? p : c * (1.0f / 12.92f);
}

__device__ __forceinline__ float labf(float t) {
    float p = fexp2(flog2(t) * (1.0f / 3.0f));
    return t > 0.008856f ? p : 7.787f * t + (16.0f / 116.0f);
}

__device__ __forceinline__ void px(float r, float g, float b,
                                   float& L, float& a01, float& b01) {
    float lr = s2lin(r), lg = s2lin(g), lb = s2lin(b);
    // RGB2XYZ rows pre-divided by D65 white (0.95047, 1.0, 1.08883)
    float X = 0.43395300f * lr + 0.37621900f * lg + 0.18982460f * lb;
    float Y = 0.21267100f * lr + 0.71516000f * lg + 0.07216900f * lb;
    float Z = 0.01775660f * lr + 0.10946970f * lg + 0.87270740f * lb;
    float fx = labf(X), fy = labf(Y), fz = labf(Z);
    L   = 116.0f * fy - 16.0f;                              // L in [0,100]
    a01 = (500.0f * (fx - fy) + 128.0f) * (1.0f / 255.0f);
    b01 = (200.0f * (fy - fz) + 128.0f) * (1.0f / 255.0f);
}

// Process 4 consecutive pixels held in 3 float4 registers, in place.
// Lab layout after this: A = {L0,a0,b0,L1}, B = {a1,b1,L2,a2}, C = {b2,L3,a3,b3}
// -> L slots are A.x, A.w, B.z, C.y (rescaled later).
__device__ __forceinline__ void chunk4(float4& A, float4& B, float4& C,
                                       float& m1, float& m2) {
    float L, a, b;
    px(A.x, A.y, A.z, L, a, b); m1 = fminf(m1, L); m2 = fminf(m2, 100.0f - L);
    A.x = L; A.y = a; A.z = b;
    px(A.w, B.x, B.y, L, a, b); m1 = fminf(m1, L); m2 = fminf(m2, 100.0f - L);
    A.w = L; B.x = a; B.y = b;
    px(B.z, B.w, C.x, L, a, b); m1 = fminf(m1, L); m2 = fminf(m2, 100.0f - L);
    B.z = L; B.w = a; C.x = b;
    px(C.y, C.z, C.w, L, a, b); m1 = fminf(m1, L); m2 = fminf(m2, 100.0f - L);
    C.y = L; C.z = a; C.w = b;
}

// One block per image (16384 px), 1024 threads x 16 px.
// All 12 float4 loads issued up front (12 VMEM in flight per wave), Lab computed
// in place in registers at full f32 precision, block min-reduce, rescale L slots,
// 12 float4 stores. Single launch, no workspace.
// __launch_bounds__(1024, 4): VGPR cap 128 — the ~48 live floats of Lab state
// MUST fit in registers ((1024,8) capped at 32 VGPR -> scratch spill, +220 MB
// HBM traffic, 125 us. Latency hiding here comes from 12-deep load ILP, not
// occupancy).
__global__ __launch_bounds__(1024, 4) void k_fused(const float* __restrict__ x,
                                                   float* __restrict__ out) {
    const int img = blockIdx.x, t = threadIdx.x;
    const size_t base4 = (size_t)img * 12288;          // float4s per image
    const float4* __restrict__ in4 = (const float4*)x + base4;
    float4* __restrict__ o4 = (float4*)out + base4;

    // thread t, chunk c covers pixels 4*(t + 1024*c) .. +3  => float4s c*3072 + 3t + j
    float4 f[12];
#pragma unroll
    for (int c = 0; c < 4; ++c)
#pragma unroll
        for (int j = 0; j < 3; ++j)
            f[c * 3 + j] = in4[c * 3072 + 3 * t + j];

    float m1 = 3.4e38f, m2 = 3.4e38f;                  // min(L), min(100-L)
#pragma unroll
    for (int c = 0; c < 4; ++c)
        chunk4(f[c * 3], f[c * 3 + 1], f[c * 3 + 2], m1, m2);

    // wave reduce (64 lanes), then block reduce via tiny LDS
#pragma unroll
    for (int m = 32; m; m >>= 1) {
        m1 = fminf(m1, __shfl_xor(m1, m, 64));
        m2 = fminf(m2, __shfl_xor(m2, m, 64));
    }
    __shared__ float sm[32];                           // 16 waves x {minL, min(100-L)}
    if ((t & 63) == 0) { sm[(t >> 6) * 2] = m1; sm[(t >> 6) * 2 + 1] = m2; }
    __syncthreads();
    float Lmin = 3.4e38f, M2 = 3.4e38f;
#pragma unroll
    for (int i = 0; i < 16; ++i) {                     // broadcast reads, conflict-free
        Lmin = fminf(Lmin, sm[2 * i]);
        M2   = fminf(M2,   sm[2 * i + 1]);
    }
    const float s = 1.0f / ((100.0f - M2) - Lmin);

#pragma unroll
    for (int c = 0; c < 4; ++c) {                      // rescale the 4 L slots per chunk
        f[c * 3].x     = (f[c * 3].x     - Lmin) * s;
        f[c * 3].w     = (f[c * 3].w     - Lmin) * s;
        f[c * 3 + 1].z = (f[c * 3 + 1].z - Lmin) * s;
        f[c * 3 + 2].y = (f[c * 3 + 2].y - Lmin) * s;
    }

#pragma unroll
    for (int c = 0; c < 4; ++c)
#pragma unroll
        for (int j = 0; j < 3; ++j)
            o4[c * 3072 + 3 * t + j] = f[c * 3 + j];
}

extern "C" void kernel_launch(void* const* d_in, const int* in_sizes, int n_in,
                              void* d_out, int out_size, void* d_ws, size_t ws_size,
                              hipStream_t stream) {
    (void)in_sizes; (void)n_in; (void)out_size; (void)d_ws; (void)ws_size;
    const float* x = (const float*)d_in[0];
    float* out = (float*)d_out;
    k_fused<<<512, 1024, 0, stream>>>(x, out);
}